// Round 11
// baseline (202.912 us; speedup 1.0000x reference)
//
#include <hip/hip_runtime.h>
#include <hip/hip_bf16.h>

typedef __attribute__((ext_vector_type(8))) short bf16x8;
typedef __attribute__((ext_vector_type(4))) float f32x4;

// ---------------------------------------------------------------------------
// bf16 helpers (manual RNE pack / shift unpack)
// ---------------------------------------------------------------------------
static __device__ __forceinline__ unsigned short f2bf(float f) {
    unsigned u = __float_as_uint(f);
    unsigned r = (u + 0x7FFFu + ((u >> 16) & 1u)) >> 16;   // round-nearest-even
    return (unsigned short)r;
}
static __device__ __forceinline__ float bfLo(unsigned d) { return __uint_as_float(d << 16); }
static __device__ __forceinline__ float bfHi(unsigned d) { return __uint_as_float(d & 0xFFFF0000u); }

#define PB 128                    // partition blocks
#define PART_TPB 1024             // 16 waves/block for latency hiding
#define BUCKET 32
#define CHUNK 2048

// ---------------------------------------------------------------------------
// MFMA GEMM: support[N,128](bf16) = A[N,128](fp32) @ W[128,128](fp32).
// [verified by round-9/10 pass]
// ---------------------------------------------------------------------------
__global__ __launch_bounds__(256, 2) void mfma_gemm_kernel(const float* __restrict__ A,
                                                           const float* __restrict__ W,
                                                           unsigned short* __restrict__ S,
                                                           int N) {
    __shared__ float sW[128 * 128];   // 64 KB, [k][c]
    const int t = threadIdx.x;
    const int w = t >> 6;
    const int l = t & 63;
    const int l15 = l & 15;
    const int lq = l >> 4;
    const int row0 = blockIdx.x * 128;

    for (int i = t * 4; i < 128 * 128; i += 256 * 4)
        *(float4*)&sW[i] = *(const float4*)&W[i];
    __syncthreads();

    bf16x8 bfrag[8][4];
#pragma unroll
    for (int tc = 0; tc < 8; ++tc) {
#pragma unroll
        for (int ks = 0; ks < 4; ++ks) {
            const int c = tc * 16 + l15;
            const int k0 = ks * 32 + lq * 8;
            bf16x8 f;
#pragma unroll
            for (int i = 0; i < 8; ++i)
                f[i] = (short)f2bf(sW[(k0 + i) * 128 + c]);
            bfrag[tc][ks] = f;
        }
    }

    f32x4 acc[2][8];
#pragma unroll
    for (int rt = 0; rt < 2; ++rt)
#pragma unroll
        for (int tc = 0; tc < 8; ++tc)
            acc[rt][tc] = (f32x4){0.f, 0.f, 0.f, 0.f};

    const int wrow = row0 + w * 32;
#pragma unroll
    for (int ks = 0; ks < 4; ++ks) {
        bf16x8 afrag[2];
#pragma unroll
        for (int rt = 0; rt < 2; ++rt) {
            const int r = wrow + rt * 16 + l15;
            bf16x8 f = (bf16x8){0, 0, 0, 0, 0, 0, 0, 0};
            if (r < N) {
                const float* p = &A[(size_t)r * 128 + ks * 32 + lq * 8];
                float4 v0 = *(const float4*)p;
                float4 v1 = *(const float4*)(p + 4);
                f[0] = (short)f2bf(v0.x); f[1] = (short)f2bf(v0.y);
                f[2] = (short)f2bf(v0.z); f[3] = (short)f2bf(v0.w);
                f[4] = (short)f2bf(v1.x); f[5] = (short)f2bf(v1.y);
                f[6] = (short)f2bf(v1.z); f[7] = (short)f2bf(v1.w);
            }
            afrag[rt] = f;
        }
#pragma unroll
        for (int rt = 0; rt < 2; ++rt)
#pragma unroll
            for (int tc = 0; tc < 8; ++tc)
                acc[rt][tc] = __builtin_amdgcn_mfma_f32_16x16x32_bf16(
                    afrag[rt], bfrag[tc][ks], acc[rt][tc], 0, 0, 0);
    }

#pragma unroll
    for (int rt = 0; rt < 2; ++rt) {
#pragma unroll
        for (int j = 0; j < 4; ++j) {
            const int r = wrow + rt * 16 + lq * 4 + j;
            if (r < N) {
                unsigned short* Sp = S + (size_t)r * 128;
#pragma unroll
                for (int tc = 0; tc < 8; ++tc)
                    Sp[tc * 16 + l15] = f2bf(acc[rt][tc][j]);
            }
        }
    }
}

// ---------------------------------------------------------------------------
// Block-local CSR partition. Block p owns rec[p*chunkRecs .. +chunkRecs) and
// writes offs[p][0..nbuck] (bucket segment starts within its region; entry
// nbuck = total). All record writes land in the block's OWN region -> no
// cross-XCD line ping-pong; no global cursor; no overflow possible.
// Per edge e: r=ei[e], c=ei[e+E], rr=rel[e]; emit (dst=r,src=c),(dst=c,src=r).
// Record: src (17b) | rel (8b, <<17) | dstLocal (5b, <<25).
// ---------------------------------------------------------------------------
__global__ __launch_bounds__(PART_TPB) void partition_kernel(
        const int* __restrict__ ei, const int* __restrict__ rel,
        unsigned* __restrict__ offs, unsigned* __restrict__ rec,
        int E, int nbuck, int chunkE, int chunkRecs) {
    extern __shared__ unsigned sh[];   // hist[nbuck] | cur[nbuck] | tmp[PART_TPB]
    unsigned* hist = sh;
    unsigned* cur  = sh + nbuck;
    unsigned* tmp  = cur + nbuck;
    const int t = threadIdx.x;
    const int p = blockIdx.x;
    const long long start = (long long)p * chunkE;
    long long end = start + chunkE; if (end > E) end = E;

    for (int i = t; i < nbuck; i += PART_TPB) hist[i] = 0u;
    __syncthreads();
    for (long long e = start + t; e < end; e += PART_TPB) {
        unsigned r = (unsigned)ei[e];
        unsigned c = (unsigned)ei[e + E];
        atomicAdd(&hist[r >> 5], 1u);
        atomicAdd(&hist[c >> 5], 1u);
    }
    __syncthreads();

    // blocked exclusive scan of hist[0..nbuck): thread t owns [t*per, t*per+per)
    const int per = (nbuck + PART_TPB - 1) / PART_TPB;
    const int base0 = t * per;
    unsigned lsum = 0;
    for (int i = 0; i < per; ++i) {
        int idx = base0 + i;
        if (idx < nbuck) lsum += hist[idx];
    }
    tmp[t] = lsum;
    __syncthreads();
    for (int d = 1; d < PART_TPB; d <<= 1) {
        unsigned x = (t >= d) ? tmp[t - d] : 0u;
        __syncthreads();
        tmp[t] += x;
        __syncthreads();
    }
    unsigned run = (t == 0) ? 0u : tmp[t - 1];
    for (int i = 0; i < per; ++i) {
        int idx = base0 + i;
        if (idx < nbuck) {
            unsigned c0 = hist[idx];
            hist[idx] = run;       // binStart
            cur[idx] = run;        // running cursor for fill
            run += c0;
        }
    }
    __syncthreads();

    // write offset row (coalesced); entry nbuck = total records this block
    unsigned* orow = offs + (size_t)p * (nbuck + 1);
    for (int i = t; i < nbuck; i += PART_TPB) orow[i] = hist[i];
    if (t == 0) orow[nbuck] = tmp[PART_TPB - 1];

    // fill into own region (scattered 4B, but same-CU line reuse only)
    unsigned* rbase = rec + (size_t)p * chunkRecs;
    for (long long e = start + t; e < end; e += PART_TPB) {
        unsigned r = (unsigned)ei[e];
        unsigned c = (unsigned)ei[e + E];
        unsigned rr = (unsigned)rel[e];
        unsigned p1 = atomicAdd(&cur[r >> 5], 1u);
        rbase[p1] = c | (rr << 17) | ((r & 31u) << 25);
        unsigned p2 = atomicAdd(&cur[c >> 5], 1u);
        rbase[p2] = r | (rr << 17) | ((c & 31u) << 25);
    }
}

// ---------------------------------------------------------------------------
// Gather: block = 32-node bucket. Reads its PB segments (offs meta), batches
// them into LDS raw[] windows, counting-sorts each window by dstLocal, then
// each half-wave accumulates its 4 nodes' contiguous runs into float4
// registers (unroll-8, 8 loads in flight). Single coalesced out-write.
// ---------------------------------------------------------------------------
static __device__ __forceinline__ void accum_run(const unsigned short* __restrict__ support,
                                                 const unsigned* sorted,
                                                 const float* aLds,
                                                 unsigned s0, unsigned cq, int lane,
                                                 float4& acc) {
    unsigned j = 0;
    for (; j + 8 <= cq; j += 8) {
        unsigned rr[8]; uint2 qq[8]; float aa[8];
#pragma unroll
        for (int u = 0; u < 8; ++u) rr[u] = sorted[s0 + j + u];
#pragma unroll
        for (int u = 0; u < 8; ++u)
            qq[u] = ((const uint2*)(support + (size_t)(rr[u] & 0x1FFFFu) * 128))[lane];
#pragma unroll
        for (int u = 0; u < 8; ++u) aa[u] = aLds[(rr[u] >> 17) & 0xFFu];
#pragma unroll
        for (int u = 0; u < 8; ++u) {
            acc.x += aa[u] * bfLo(qq[u].x);
            acc.y += aa[u] * bfHi(qq[u].x);
            acc.z += aa[u] * bfLo(qq[u].y);
            acc.w += aa[u] * bfHi(qq[u].y);
        }
    }
    for (; j < cq; ++j) {
        unsigned r0 = sorted[s0 + j];
        uint2 q0 = ((const uint2*)(support + (size_t)(r0 & 0x1FFFFu) * 128))[lane];
        float a0 = aLds[(r0 >> 17) & 0xFFu];
        acc.x += a0 * bfLo(q0.x); acc.y += a0 * bfHi(q0.x);
        acc.z += a0 * bfLo(q0.y); acc.w += a0 * bfHi(q0.y);
    }
}

__global__ __launch_bounds__(256) void gather_bucket_kernel(const unsigned short* __restrict__ support,
                                                            const unsigned* __restrict__ rec,
                                                            const unsigned* __restrict__ offs,
                                                            const float* __restrict__ alpha,
                                                            const float* __restrict__ bias,
                                                            float* __restrict__ out,
                                                            int N, int nAlpha, int nbuck,
                                                            int chunkRecs) {
    __shared__ float aLds[256];
    __shared__ unsigned raw[CHUNK];
    __shared__ unsigned sorted[CHUNK];
    __shared__ unsigned segS[PB];      // absolute rec index of segment start
    __shared__ unsigned segL[PB];      // segment length
    __shared__ unsigned segD[PB];      // inclusive prefix of lengths
    __shared__ unsigned scnt[BUCKET], sstart[BUCKET], scur[BUCKET];

    const int t = threadIdx.x;
    const int b = blockIdx.x;
    const int lane = t & 31;
    const int hw = t >> 5;

    {   // stage alpha; row 0 (padding) forced to zero
        float a = 0.f;
        if (t > 0 && t < nAlpha) a = alpha[t];
        aLds[t] = a;
    }
    const float4 b4 = *(const float4*)&bias[lane * 4];

    // segment metadata
    if (t < PB) {
        const unsigned* orow = offs + (size_t)t * (nbuck + 1);
        unsigned s = orow[b];
        unsigned e2 = orow[b + 1];
        segS[t] = (unsigned)t * (unsigned)chunkRecs + s;
        segL[t] = e2 - s;
    }
    __syncthreads();
    if (t < PB) segD[t] = segL[t];
    __syncthreads();
    for (int d = 1; d < PB; d <<= 1) {
        unsigned x = (t < PB && t >= d) ? segD[t - d] : 0u;
        __syncthreads();
        if (t < PB) segD[t] += x;
        __syncthreads();
    }
    const unsigned T = segD[PB - 1];

    float4 acc0 = make_float4(0.f, 0.f, 0.f, 0.f);
    float4 acc1 = make_float4(0.f, 0.f, 0.f, 0.f);
    float4 acc2 = make_float4(0.f, 0.f, 0.f, 0.f);
    float4 acc3 = make_float4(0.f, 0.f, 0.f, 0.f);

    const int seg = t & (PB - 1);
    const int half = t >> 7;            // 2 threads per segment

    for (unsigned w0 = 0; w0 < T; w0 += CHUNK) {
        const unsigned w1 = min(w0 + (unsigned)CHUNK, T);
        const unsigned cc = w1 - w0;
        __syncthreads();                 // protect raw/sorted from prev batch
        if (t < BUCKET) scnt[t] = 0u;
        __syncthreads();

        // copy window [w0,w1) into raw + histogram by dstLocal
        {
            unsigned incl = segD[seg], len = segL[seg];
            unsigned gs = incl - len;    // global start of this segment
            unsigned lo = gs > w0 ? gs : w0;
            unsigned hi = incl < w1 ? incl : w1;
            for (unsigned g = lo + half; g < hi; g += 2) {
                unsigned v = rec[segS[seg] + (g - gs)];
                raw[g - w0] = v;
                atomicAdd(&scnt[v >> 25], 1u);
            }
        }
        __syncthreads();

        // exclusive scan of 32 counters (shfl, lanes 0-31 of wave 0)
        if (t < BUCKET) {
            unsigned c = scnt[t];
            unsigned x = c;
#pragma unroll
            for (int d = 1; d < BUCKET; d <<= 1) {
                unsigned y = __shfl_up(x, d, BUCKET);
                if (t >= d) x += y;
            }
            sstart[t] = x - c;
            scur[t] = x - c;
        }
        __syncthreads();

        // scatter into node-sorted LDS order
        for (int k = 0; k < 8; ++k) {
            unsigned i = (unsigned)(k * 256 + t);
            if (i < cc) {
                unsigned v = raw[i];
                unsigned pos = atomicAdd(&scur[v >> 25], 1u);
                sorted[pos] = v;
            }
        }
        __syncthreads();

        // register accumulation, 4 nodes per half-wave
        accum_run(support, sorted, aLds, sstart[hw * 4 + 0], scnt[hw * 4 + 0], lane, acc0);
        accum_run(support, sorted, aLds, sstart[hw * 4 + 1], scnt[hw * 4 + 1], lane, acc1);
        accum_run(support, sorted, aLds, sstart[hw * 4 + 2], scnt[hw * 4 + 2], lane, acc2);
        accum_run(support, sorted, aLds, sstart[hw * 4 + 3], scnt[hw * 4 + 3], lane, acc3);
    }

    // write out + bias, coalesced, single writer
    const int node0 = b * BUCKET + hw * 4;
#define WRITE_NODE(Q, ACC)                                                          \
    {                                                                               \
        int node = node0 + (Q);                                                     \
        if (node < N) {                                                             \
            float4 o = make_float4(ACC.x + b4.x, ACC.y + b4.y,                      \
                                   ACC.z + b4.z, ACC.w + b4.w);                     \
            *(float4*)&out[(size_t)node * 128 + lane * 4] = o;                      \
        }                                                                           \
    }
    WRITE_NODE(0, acc0)
    WRITE_NODE(1, acc1)
    WRITE_NODE(2, acc2)
    WRITE_NODE(3, acc3)
#undef WRITE_NODE
}

// ---------------------------------------------------------------------------
// Fallback path (constraints not met): VALU gemm + bias-init + atomic scatter
// ---------------------------------------------------------------------------
__global__ __launch_bounds__(256) void gemm_kernel(const float* __restrict__ A,
                                                   const float* __restrict__ W,
                                                   unsigned short* __restrict__ S,
                                                   int N) {
    __shared__ float sIn[128][33];
    __shared__ float sW[32][128];
    const int tid = threadIdx.x;
    const int tx = tid & 15;
    const int ty = tid >> 4;
    const int row0 = blockIdx.x * 128;
    float acc[8][8];
#pragma unroll
    for (int i = 0; i < 8; ++i)
#pragma unroll
        for (int j = 0; j < 8; ++j) acc[i][j] = 0.f;
    for (int kc = 0; kc < 128; kc += 32) {
#pragma unroll
        for (int p = 0; p < 4; ++p) {
            int r = p * 32 + (tid >> 3);
            int q = tid & 7;
            int grow = row0 + r;
            float4 v = make_float4(0.f, 0.f, 0.f, 0.f);
            if (grow < N) v = *(const float4*)&A[(size_t)grow * 128 + kc + q * 4];
            sIn[r][q * 4 + 0] = v.x; sIn[r][q * 4 + 1] = v.y;
            sIn[r][q * 4 + 2] = v.z; sIn[r][q * 4 + 3] = v.w;
        }
#pragma unroll
        for (int p = 0; p < 4; ++p) {
            int kr = p * 8 + (tid >> 5);
            int c4 = tid & 31;
            *(float4*)&sW[kr][c4 * 4] = *(const float4*)&W[(size_t)(kc + kr) * 128 + c4 * 4];
        }
        __syncthreads();
#pragma unroll
        for (int k = 0; k < 32; ++k) {
            float a[8];
#pragma unroll
            for (int i = 0; i < 8; ++i) a[i] = sIn[ty * 8 + i][k];
            float4 w0 = *(float4*)&sW[k][tx * 4];
            float4 w1 = *(float4*)&sW[k][64 + tx * 4];
#pragma unroll
            for (int i = 0; i < 8; ++i) {
                acc[i][0] += a[i] * w0.x; acc[i][1] += a[i] * w0.y;
                acc[i][2] += a[i] * w0.z; acc[i][3] += a[i] * w0.w;
                acc[i][4] += a[i] * w1.x; acc[i][5] += a[i] * w1.y;
                acc[i][6] += a[i] * w1.z; acc[i][7] += a[i] * w1.w;
            }
        }
        __syncthreads();
    }
#pragma unroll
    for (int i = 0; i < 8; ++i) {
        int grow = row0 + ty * 8 + i;
        if (grow < N) {
            unsigned short* Sp = S + (size_t)grow * 128;
            unsigned a0 = (unsigned)f2bf(acc[i][0]) | ((unsigned)f2bf(acc[i][1]) << 16);
            unsigned a1 = (unsigned)f2bf(acc[i][2]) | ((unsigned)f2bf(acc[i][3]) << 16);
            unsigned a2 = (unsigned)f2bf(acc[i][4]) | ((unsigned)f2bf(acc[i][5]) << 16);
            unsigned a3 = (unsigned)f2bf(acc[i][6]) | ((unsigned)f2bf(acc[i][7]) << 16);
            *(uint2*)&Sp[tx * 4] = make_uint2(a0, a1);
            *(uint2*)&Sp[64 + tx * 4] = make_uint2(a2, a3);
        }
    }
}

__global__ __launch_bounds__(256) void init_out_kernel(float* __restrict__ out,
                                                       const float* __restrict__ bias,
                                                       long long total4) {
    long long i = (long long)blockIdx.x * blockDim.x + threadIdx.x;
    if (i >= total4) return;
    float4 b = ((const float4*)bias)[(int)(i & 31)];
    ((float4*)out)[i] = b;
}

__global__ __launch_bounds__(256) void scatter_kernel(const unsigned short* __restrict__ support,
                                                      const int* __restrict__ ei,
                                                      const int* __restrict__ rel,
                                                      const float* __restrict__ alpha,
                                                      float* __restrict__ out,
                                                      int E) {
    long long tid = (long long)blockIdx.x * blockDim.x + threadIdx.x;
    long long mid = tid >> 5;
    if (mid >= 2LL * E) return;
    int lane4 = (int)(tid & 31);
    int dst = ei[mid];
    long long ms = (mid < E) ? mid + E : mid - E;
    int src = ei[ms];
    int e = (int)((mid < E) ? mid : mid - E);
    int rr = rel[e];
    float alp = (rr == 0) ? 0.f : alpha[rr];
    if (alp == 0.f) return;
    uint2 q = ((const uint2*)(support + (size_t)src * 128))[lane4];
    float* o = &out[(size_t)dst * 128 + lane4 * 4];
    atomicAdd(o + 0, alp * bfLo(q.x));
    atomicAdd(o + 1, alp * bfHi(q.x));
    atomicAdd(o + 2, alp * bfLo(q.y));
    atomicAdd(o + 3, alp * bfHi(q.y));
}

extern "C" void kernel_launch(void* const* d_in, const int* in_sizes, int n_in,
                              void* d_out, int out_size, void* d_ws, size_t ws_size,
                              hipStream_t stream) {
    const float* input  = (const float*)d_in[0];
    const int*   ei     = (const int*)d_in[1];    // int32 per harness contract
    const int*   rel    = (const int*)d_in[2];
    const float* weight = (const float*)d_in[4];
    const float* alpha  = (const float*)d_in[5];
    const float* bias   = (const float*)d_in[6];
    float*       out    = (float*)d_out;

    const int N = in_sizes[0] / 128;
    const int E = in_sizes[2];
    const int nAlpha = in_sizes[5];               // N_REL + 1
    const long long M = 2LL * E;
    const int nbuck = (N + BUCKET - 1) / BUCKET;

    const int chunkE = (E + PB - 1) / PB;
    const int chunkRecs = 2 * chunkE;

    // workspace layout
    char* ws = (char*)d_ws;
    const size_t supB  = ((size_t)N * 128 * 2 + 255) & ~(size_t)255;   // bf16 support
    const size_t offsB = ((size_t)PB * (nbuck + 1) * 4 + 255) & ~(size_t)255;
    unsigned short* support = (unsigned short*)ws;
    unsigned* offs = (unsigned*)(ws + supB);
    unsigned* rec  = (unsigned*)(ws + supB + offsB);
    const size_t need = supB + offsB + (size_t)PB * chunkRecs * 4;

    const int gemmBlocks = (N + 127) / 128;
    const size_t partShmem = (size_t)(2 * nbuck + PART_TPB) * 4;   // hist+cur+tmp
    const bool okMain = (ws_size >= need) && (N <= (1 << 17)) && (nAlpha <= 256) &&
                        (nbuck <= 4096);

    if (okMain) {
        partition_kernel<<<PB, PART_TPB, partShmem, stream>>>(
            ei, rel, offs, rec, E, nbuck, chunkE, chunkRecs);
        mfma_gemm_kernel<<<gemmBlocks, 256, 0, stream>>>(input, weight, support, N);
        gather_bucket_kernel<<<nbuck, 256, 0, stream>>>(
            support, rec, offs, alpha, bias, out, N, nAlpha, nbuck, chunkRecs);
    } else {
        gemm_kernel<<<gemmBlocks, 256, 0, stream>>>(input, weight, support, N);
        long long total4 = (long long)N * 32;
        init_out_kernel<<<(int)((total4 + 255) / 256), 256, 0, stream>>>(out, bias, total4);
        long long tthreads = M * 32;
        scatter_kernel<<<(int)((tthreads + 255) / 256), 256, 0, stream>>>(
            support, ei, rel, alpha, out, E);
    }
}